// Round 8
// baseline (276.763 us; speedup 1.0000x reference)
//
#include <hip/hip_runtime.h>
#include <hip/hip_bf16.h>

// Problem constants (B=4, T=2048, C=1024, H=16, HD=64)
#define BB 4
#define TT 2048
#define CC 1024
#define HH 16
#define HD 64

typedef _Float16 half8 __attribute__((ext_vector_type(8)));
typedef _Float16 half4 __attribute__((ext_vector_type(4)));
typedef _Float16 half2_t __attribute__((ext_vector_type(2)));
typedef __fp16 fp16x2 __attribute__((ext_vector_type(2)));
typedef float floatx4 __attribute__((ext_vector_type(4)));
typedef float floatx16 __attribute__((ext_vector_type(16)));
typedef int intx2 __attribute__((ext_vector_type(2)));
typedef int intx4 __attribute__((ext_vector_type(4)));

// async global->LDS, 16B per lane (dest = wave-uniform base + lane*16)
__device__ __forceinline__ void async_cp16(const void* g, void* l) {
    __builtin_amdgcn_global_load_lds(
        (const __attribute__((address_space(1))) unsigned int*)g,
        (__attribute__((address_space(3))) unsigned int*)l,
        16, 0, 0);
}

// raw v_exp_f32 — args <= 8 (defer-max THR) so no overflow; very negative
// args underflow to 0 in HW which is exactly softmax semantics.
__device__ __forceinline__ float exp2_raw(float x) {
    return __builtin_amdgcn_exp2f(x);
}

// pack 2 f32 -> dword of 2 fp16 via v_cvt_pkrtz
__device__ __forceinline__ int pkh(float a, float b) {
    fp16x2 v = __builtin_amdgcn_cvt_pkrtz(a, b);
    return __builtin_bit_cast(int, v);
}

// max over a f32x16 accumulator, max3-friendly
__device__ __forceinline__ float maxv16(floatx16 s) {
    float a0 = fmaxf(fmaxf(s[0], s[1]), s[2]);
    float a1 = fmaxf(fmaxf(s[3], s[4]), s[5]);
    float a2 = fmaxf(fmaxf(s[6], s[7]), s[8]);
    float a3 = fmaxf(fmaxf(s[9], s[10]), s[11]);
    float a4 = fmaxf(fmaxf(s[12], s[13]), s[14]);
    float b0 = fmaxf(fmaxf(a0, a1), a2);
    float b1 = fmaxf(fmaxf(a3, a4), s[15]);
    return fmaxf(b0, b1);
}

// Assemble one 16-key B-frag (32x32x16, 8 fp16) from 4 cvtpk dwords.
// (verified round 5/6: passed absmax)
__device__ __forceinline__ half8 assembleF(int a, int b, int c, int d) {
    intx2 s1 = __builtin_amdgcn_permlane32_swap(a, c, false, false);
    intx2 s2 = __builtin_amdgcn_permlane32_swap(b, d, false, false);
    intx4 w = {s1[0], s2[0], s1[1], s2[1]};
    return __builtin_bit_cast(half8, w);
}

// ---------------------------------------------------------------------------
// fp32 -> fp16 conversion, 8 elements/thread
// ---------------------------------------------------------------------------
__global__ void cvt_f32_f16(const float* __restrict__ src, _Float16* __restrict__ dst, int n) {
    int i = (blockIdx.x * blockDim.x + threadIdx.x) * 8;
    if (i < n) {
        float4 v0 = *(const float4*)(src + i);
        float4 v1 = *(const float4*)(src + i + 4);
        half8 h;
        h[0] = (_Float16)v0.x; h[1] = (_Float16)v0.y; h[2] = (_Float16)v0.z; h[3] = (_Float16)v0.w;
        h[4] = (_Float16)v1.x; h[5] = (_Float16)v1.y; h[6] = (_Float16)v1.z; h[7] = (_Float16)v1.w;
        *(half8*)(dst + i) = h;
    }
}

// ---------------------------------------------------------------------------
// 256x256 QKV GEMM, counted-vmcnt pipeline (T3+T4), T2 swizzle, T5 setprio.
// 8 waves (2M x 4N), per-wave 128x64 output, BK=64, 2 K-tiles in flight.
// LDS 128KB: 2 buffers x (A 256x64 + B 256x64) fp16.
//
// T2 swizzle (rule-21-correct with global_load_lds): LDS dest stays LINEAR
// (tid*16B); the SOURCE column chunk is pre-permuted: chunk' = chunk ^ (row&7).
// Frag reads apply the same XOR; row&7 == lane&7 for every frag row
// (rows are base16*k + lc), so the read-side XOR is a per-lane constant.
//
// vmcnt ledger: stage(t+2) [8 loads] issued after compute-barrier of iter t.
// Top of iter t: outstanding = {t:8, t+1:8} -> s_waitcnt vmcnt(8) waits
// exactly for tile t. Never drains to 0 in steady state.
// ---------------------------------------------------------------------------
__global__ __launch_bounds__(512, 2) void hgemm256_qkv(
    const _Float16* __restrict__ A, const _Float16* __restrict__ Bw,
    const float* __restrict__ bias,
    _Float16* __restrict__ q_out, _Float16* __restrict__ k_out, _Float16* __restrict__ v_out,
    int M, int N, int K)
{
    __shared__ __attribute__((aligned(16))) _Float16 LA[2 * 256 * 64];  // 64KB
    __shared__ __attribute__((aligned(16))) _Float16 LB[2 * 256 * 64];  // 64KB

    const int tid  = threadIdx.x;
    const int lane = tid & 63;
    const int wave = tid >> 6;
    const int quad = lane >> 4;
    const int lc   = lane & 15;
    const int wr   = wave >> 2;      // 0..1  M-half
    const int wn   = wave & 3;       // 0..3  N-quarter
    const size_t bm = (size_t)blockIdx.y * 256;
    const size_t bn = (size_t)blockIdx.x * 256;

    // staging map: row = rnd*64 + (tid>>3), chunk = tid&7; source pre-swizzled
    const int srow  = tid >> 3;                  // 0..63
    const int sphys = (tid & 7) ^ (srow & 7);    // row&7 invariant across rnds (64|step)
    const _Float16* Asrc = A + (bm + srow) * (size_t)K + sphys * 8;
    const _Float16* Bsrc = Bw + (bn + srow) * (size_t)K + sphys * 8;
    const size_t rquad = (size_t)64 * K;         // 64-row source step

    const int xr = lc & 7;                       // read-side XOR (per-lane const)

    floatx4 acc[8][4] = {};

#define STAGE256(bufi, kk) do {                                         \
        _Float16* da = LA + (bufi) * 16384 + tid * 8;                   \
        _Float16* db = LB + (bufi) * 16384 + tid * 8;                   \
        const _Float16* sa = Asrc + (kk);                               \
        const _Float16* sb = Bsrc + (kk);                               \
        async_cp16(sa,             da);                                 \
        async_cp16(sa + rquad,     da + 4096);                          \
        async_cp16(sa + 2 * rquad, da + 8192);                          \
        async_cp16(sa + 3 * rquad, da + 12288);                         \
        async_cp16(sb,             db);                                 \
        async_cp16(sb + rquad,     db + 4096);                          \
        async_cp16(sb + 2 * rquad, db + 8192);                          \
        async_cp16(sb + 3 * rquad, db + 12288);                         \
    } while (0)

    STAGE256(0, 0);
    STAGE256(1, 64);

    const int NTT = K / 64;   // 16
    for (int t = 0; t < NTT; ++t) {
        if (t < NTT - 2) asm volatile("s_waitcnt vmcnt(8)" ::: "memory");
        else             asm volatile("s_waitcnt vmcnt(0)" ::: "memory");
        __builtin_amdgcn_s_barrier();
        __builtin_amdgcn_sched_barrier(0);

        const _Float16* Abuf = LA + (t & 1) * 16384;
        const _Float16* Bbuf = LB + (t & 1) * 16384;

        // B frags: 4 N-reps x 2 k-halves (resident whole K-tile)
        half8 bf[4][2];
#pragma unroll
        for (int nt = 0; nt < 4; nt++) {
            int row = wn * 64 + nt * 16 + lc;
#pragma unroll
            for (int kh = 0; kh < 2; kh++)
                bf[nt][kh] = *(const half8*)(Bbuf + row * 64 + ((kh * 4 + quad) ^ xr) * 8);
        }
        // two phases: M-half 0 then M-half 1 (A frags reloaded per half)
#pragma unroll
        for (int mh = 0; mh < 2; mh++) {
            half8 af[4][2];
#pragma unroll
            for (int mt = 0; mt < 4; mt++) {
                int row = wr * 128 + mh * 64 + mt * 16 + lc;
#pragma unroll
                for (int kh = 0; kh < 2; kh++)
                    af[mt][kh] = *(const half8*)(Abuf + row * 64 + ((kh * 4 + quad) ^ xr) * 8);
            }
            __builtin_amdgcn_s_setprio(1);
#pragma unroll
            for (int mt = 0; mt < 4; mt++)
#pragma unroll
                for (int nt = 0; nt < 4; nt++) {
                    acc[mh * 4 + mt][nt] = __builtin_amdgcn_mfma_f32_16x16x32_f16(
                        af[mt][0], bf[nt][0], acc[mh * 4 + mt][nt], 0, 0, 0);
                    acc[mh * 4 + mt][nt] = __builtin_amdgcn_mfma_f32_16x16x32_f16(
                        af[mt][1], bf[nt][1], acc[mh * 4 + mt][nt], 0, 0, 0);
                }
            __builtin_amdgcn_s_setprio(0);
        }
        __builtin_amdgcn_s_barrier();
        __builtin_amdgcn_sched_barrier(0);
        if (t + 2 < NTT) STAGE256(t & 1, (t + 2) * 64);
    }
#undef STAGE256

    // epilogue: scatter -> Q(scaled)/K/V fp16 [B*H, T, 64]
#pragma unroll
    for (int MT = 0; MT < 8; MT++) {
        int mbase = (int)bm + wr * 128 + MT * 16 + quad * 4;
#pragma unroll
        for (int nt = 0; nt < 4; nt++) {
            int n = (int)bn + wn * 64 + nt * 16 + lc;
            float bv = bias[n];
#pragma unroll
            for (int r = 0; r < 4; r++) {
                float v = acc[MT][nt][r] + bv;
                int mm = mbase + r;
                int seg = n >> 10;        // 0=Q 1=K 2=V
                int cm  = n & 1023;
                int h = cm >> 6, d = cm & 63;
                int bb = mm >> 11, tt = mm & 2047;
                size_t dst = (((size_t)(bb * HH + h)) * TT + tt) * HD + d;
                if (seg == 0)      q_out[dst] = (_Float16)(v * 0.18033688f);
                else if (seg == 1) k_out[dst] = (_Float16)v;
                else               v_out[dst] = (_Float16)v;
            }
        }
    }
}

// ---------------------------------------------------------------------------
// NT GEMM: 128x128 tile, BK=64 (known-good; used for the proj GEMM)
// ---------------------------------------------------------------------------
__global__ __launch_bounds__(256) void hgemm_nt_proj(
    const _Float16* __restrict__ A, const _Float16* __restrict__ Bw,
    const float* __restrict__ bias, float* __restrict__ c_out,
    int M, int N, int K)
{
    __shared__ __attribute__((aligned(16))) _Float16 As[2 * 128 * 32];  // 16KB
    __shared__ __attribute__((aligned(16))) _Float16 Bs[2 * 128 * 32];  // 16KB

    const int tid  = threadIdx.x;
    const int lane = tid & 63;
    const int wave = tid >> 6;
    const int quad = lane >> 4;
    const int lc   = lane & 15;
    const int wr   = wave >> 1, wc = wave & 1;
    const size_t bm = (size_t)blockIdx.y * 128;
    const size_t bn = (size_t)blockIdx.x * 128;

    const int r0 = tid >> 2;        // 0..63
    const int ck = (tid & 3) * 8;   // 0,8,16,24

    const _Float16* Ap = A + (bm + r0) * (size_t)K + ck;
    const _Float16* Bp = Bw + (bn + r0) * (size_t)K + ck;
    _Float16* lA = As + tid * 8;
    _Float16* lB = Bs + tid * 8;
    const size_t rstep = (size_t)64 * K;

    floatx4 acc[4][4] = {};

    for (int kk = 0; kk < K; kk += 64) {
        __syncthreads();
        async_cp16(Ap + kk, lA);
        async_cp16(Ap + kk + rstep, lA + 2048);
        async_cp16(Ap + kk + 32, lA + 4096);
        async_cp16(Ap + kk + 32 + rstep, lA + 4096 + 2048);
        async_cp16(Bp + kk, lB);
        async_cp16(Bp + kk + rstep, lB + 2048);
        async_cp16(Bp + kk + 32, lB + 4096);
        async_cp16(Bp + kk + 32 + rstep, lB + 4096 + 2048);
        __syncthreads();

#pragma unroll
        for (int h = 0; h < 2; h++) {
            half8 af[4], bf[4];
#pragma unroll
            for (int mt = 0; mt < 4; mt++)
                af[mt] = *(const half8*)(As + h * 4096 + (wr * 64 + mt * 16 + lc) * 32 + quad * 8);
#pragma unroll
            for (int nt = 0; nt < 4; nt++)
                bf[nt] = *(const half8*)(Bs + h * 4096 + (wc * 64 + nt * 16 + lc) * 32 + quad * 8);
#pragma unroll
            for (int mt = 0; mt < 4; mt++)
#pragma unroll
                for (int nt = 0; nt < 4; nt++)
                    acc[mt][nt] = __builtin_amdgcn_mfma_f32_16x16x32_f16(af[mt], bf[nt], acc[mt][nt], 0, 0, 0);
        }
    }

#pragma unroll
    for (int mt = 0; mt < 4; mt++) {
        int mbase = (int)bm + wr * 64 + mt * 16 + quad * 4;
#pragma unroll
        for (int nt = 0; nt < 4; nt++) {
            int n = (int)bn + wc * 64 + nt * 16 + lc;
            float bv = bias[n];
#pragma unroll
            for (int r = 0; r < 4; r++)
                c_out[(size_t)(mbase + r) * N + n] = acc[mt][nt][r] + bv;
        }
    }
}

// ---------------------------------------------------------------------------
// Flash attention, 32x32 MFMA structure (unchanged from round 6).
// ---------------------------------------------------------------------------
__global__ __launch_bounds__(512) void attn_flash(
    const _Float16* __restrict__ Qp, const _Float16* __restrict__ Kp,
    const _Float16* __restrict__ Vp, _Float16* __restrict__ Op)
{
    __shared__ __attribute__((aligned(16))) _Float16 Ks[64 * 64];  // [key][dim] 8KB
    __shared__ __attribute__((aligned(16))) _Float16 Vt[64 * 64];  // [dim][key] 8KB

    const int bh   = blockIdx.x;   // 0..63 (b*16+h)
    const int qt   = blockIdx.y;   // 0..7
    const int tid  = threadIdx.x;
    const int lane = tid & 63;
    const int wave = tid >> 6;     // 0..7
    const int ql   = lane & 31;    // query (and dim-row id)
    const int hi   = lane >> 5;    // 0/1

    const size_t hb = (size_t)bh * TT * HD;

    const int qrow = qt * 256 + wave * 32 + ql;
    half8 bq[4];
#pragma unroll
    for (int c = 0; c < 4; c++)
        bq[c] = *(const half8*)(Qp + hb + (size_t)qrow * HD + c * 16 + hi * 8);

    floatx16 o0 = (floatx16)0.0f, o1 = (floatx16)0.0f;
    float mrun = -1e30f, lrun = 0.f;

    const int sk = tid >> 3;
    const int sj = tid & 7;
    const int sg = sj ^ (sk & 7);
    const _Float16* Kg = Kp + hb + (size_t)sk * HD + sg * 8;
    _Float16* KsW = Ks + tid * 8;

    const int vkp = tid >> 4;
    const int vd4 = (tid & 15) * 4;
    const _Float16* Vg0 = Vp + hb + (size_t)(2 * vkp) * HD + vd4;
    const _Float16* Vg1 = Vg0 + HD;

    half8 kv  = *(const half8*)Kg;
    half4 va0 = *(const half4*)Vg0;
    half4 vb0 = *(const half4*)Vg1;

    for (int kt = 0; kt < TT; kt += 64) {
        __syncthreads();
        *(half8*)KsW = kv;
#pragma unroll
        for (int j = 0; j < 4; j++) {
            int row = vd4 + j;
            int boff = (row * 128 + vkp * 4) ^ (((row >> 2) & 7) << 4);
            half2_t w; w[0] = va0[j]; w[1] = vb0[j];
            *(half2_t*)((char*)Vt + boff) = w;
        }
        __syncthreads();

        if (kt + 64 < TT) {
            const size_t koff = (size_t)(kt + 64) * HD;
            kv  = *(const half8*)(Kg + koff);
            va0 = *(const half4*)(Vg0 + koff);
            vb0 = *(const half4*)(Vg1 + koff);
        }

        floatx16 s0 = (floatx16)0.0f, s1 = (floatx16)0.0f;
        __builtin_amdgcn_s_setprio(1);
#pragma unroll
        for (int c = 0; c < 4; c++) {
            int offk = (ql * 128 + c * 32 + hi * 16) ^ ((ql & 7) << 4);
            half8 a0 = *(const half8*)((const char*)Ks + offk);
            half8 a1 = *(const half8*)((const char*)Ks + offk + 4096);
            s0 = __builtin_amdgcn_mfma_f32_32x32x16_f16(a0, bq[c], s0, 0, 0, 0);
            s1 = __builtin_amdgcn_mfma_f32_32x32x16_f16(a1, bq[c], s1, 0, 0, 0);
        }
        __builtin_amdgcn_s_setprio(0);

        float mx = fmaxf(maxv16(s0), maxv16(s1));
        mx = fmaxf(mx, __shfl_xor(mx, 32));
        const bool noresc = __all(mx <= mrun + 8.0f);
        const float mnew = noresc ? mrun : fmaxf(mrun, mx);
        float rs = 0.f;
        int d[16];
#pragma unroll
        for (int i = 0; i < 8; i++) {
            float e0 = exp2_raw(s0[2 * i] - mnew);
            float e1 = exp2_raw(s0[2 * i + 1] - mnew);
            rs += e0 + e1;
            d[i] = pkh(e0, e1);
        }
#pragma unroll
        for (int i = 0; i < 8; i++) {
            float e0 = exp2_raw(s1[2 * i] - mnew);
            float e1 = exp2_raw(s1[2 * i + 1] - mnew);
            rs += e0 + e1;
            d[8 + i] = pkh(e0, e1);
        }
        rs += __shfl_xor(rs, 32);
        if (!noresc) {
            float al = exp2_raw(mrun - mnew);
            mrun = mnew;
            lrun *= al;
            o0 *= al;
            o1 *= al;
        }
        lrun += rs;

        half8 F[4];
        F[0] = assembleF(d[0], d[1], d[2], d[3]);
        F[1] = assembleF(d[4], d[5], d[6], d[7]);
        F[2] = assembleF(d[8], d[9], d[10], d[11]);
        F[3] = assembleF(d[12], d[13], d[14], d[15]);

        __builtin_amdgcn_s_setprio(1);
#pragma unroll
        for (int kb = 0; kb < 4; kb++) {
            int offv = (ql * 128 + kb * 32 + hi * 16) ^ (((ql >> 2) & 7) << 4);
            half8 v0 = *(const half8*)((const char*)Vt + offv);
            half8 v1 = *(const half8*)((const char*)Vt + offv + 4096);
            o0 = __builtin_amdgcn_mfma_f32_32x32x16_f16(v0, F[kb], o0, 0, 0, 0);
            o1 = __builtin_amdgcn_mfma_f32_32x32x16_f16(v1, F[kb], o1, 0, 0, 0);
        }
        __builtin_amdgcn_s_setprio(0);
    }

    const float inv = __builtin_amdgcn_rcpf(lrun);
    const int b = bh >> 4, h = bh & 15;
    size_t base = ((size_t)(b * TT + qrow)) * CC + h * HD;
#pragma unroll
    for (int rr = 0; rr < 4; rr++) {
        half4 hv0, hv1;
#pragma unroll
        for (int t = 0; t < 4; t++) {
            hv0[t] = (_Float16)(o0[rr * 4 + t] * inv);
            hv1[t] = (_Float16)(o1[rr * 4 + t] * inv);
        }
        *(half4*)(Op + base + 8 * rr + 4 * hi) = hv0;
        *(half4*)(Op + base + 32 + 8 * rr + 4 * hi) = hv1;
    }
}

// ---------------------------------------------------------------------------
extern "C" void kernel_launch(void* const* d_in, const int* in_sizes, int n_in,
                              void* d_out, int out_size, void* d_ws, size_t ws_size,
                              hipStream_t stream) {
    const float* x      = (const float*)d_in[0];  // [B,T,C]
    const float* W_attn = (const float*)d_in[1];  // [3C,C]
    const float* b_attn = (const float*)d_in[2];  // [3C]
    const float* W_proj = (const float*)d_in[3];  // [C,C]
    const float* b_proj = (const float*)d_in[4];  // [C]
    float* out = (float*)d_out;

    const size_t SZ_XH  = (size_t)BB * TT * CC * 2;
    const size_t SZ_WA  = (size_t)3 * CC * CC * 2;
    const size_t SZ_WP  = (size_t)CC * CC * 2;
    const size_t SZ_QKV = (size_t)BB * HH * TT * HD * 2;
    size_t off = 0;
    _Float16* xh  = (_Float16*)((char*)d_ws + off); off += SZ_XH;
    _Float16* wah = (_Float16*)((char*)d_ws + off); off += SZ_WA;
    _Float16* wph = (_Float16*)((char*)d_ws + off); off += SZ_WP;
    _Float16* Qh  = (_Float16*)((char*)d_ws + off); off += SZ_QKV;
    _Float16* Kh  = (_Float16*)((char*)d_ws + off); off += SZ_QKV;
    _Float16* Vh  = (_Float16*)((char*)d_ws + off); off += SZ_QKV;
    _Float16* Ah  = (_Float16*)((char*)d_ws + off); off += SZ_XH;
    if (ws_size < off) return;

    const int NX  = BB * TT * CC;
    const int NWA = 3 * CC * CC;
    const int NWP = CC * CC;
    cvt_f32_f16<<<NX / 8 / 256, 256, 0, stream>>>(x, xh, NX);
    cvt_f32_f16<<<NWA / 8 / 256, 256, 0, stream>>>(W_attn, wah, NWA);
    cvt_f32_f16<<<NWP / 8 / 256, 256, 0, stream>>>(W_proj, wph, NWP);

    hgemm256_qkv<<<dim3(3 * CC / 256, BB * TT / 256), 512, 0, stream>>>(
        xh, wah, b_attn, Qh, Kh, Vh, BB * TT, 3 * CC, CC);

    attn_flash<<<dim3(BB * HH, TT / 256), 512, 0, stream>>>(Qh, Kh, Vh, Ah);

    hgemm_nt_proj<<<dim3(CC / 128, BB * TT / 128), 256, 0, stream>>>(
        Ah, wph, b_proj, out, BB * TT, CC, CC);
}

// Round 9
// 271.086 us; speedup vs baseline: 1.0209x; 1.0209x over previous
//
#include <hip/hip_runtime.h>
#include <hip/hip_bf16.h>

// Problem constants (B=4, T=2048, C=1024, H=16, HD=64)
#define BB 4
#define TT 2048
#define CC 1024
#define HH 16
#define HD 64

typedef _Float16 half8 __attribute__((ext_vector_type(8)));
typedef _Float16 half4 __attribute__((ext_vector_type(4)));
typedef _Float16 half2_t __attribute__((ext_vector_type(2)));
typedef __fp16 fp16x2 __attribute__((ext_vector_type(2)));
typedef float floatx4 __attribute__((ext_vector_type(4)));
typedef float floatx16 __attribute__((ext_vector_type(16)));
typedef int intx2 __attribute__((ext_vector_type(2)));
typedef int intx4 __attribute__((ext_vector_type(4)));

// async global->LDS, 16B per lane (dest = wave-uniform base + lane*16)
__device__ __forceinline__ void async_cp16(const void* g, void* l) {
    __builtin_amdgcn_global_load_lds(
        (const __attribute__((address_space(1))) unsigned int*)g,
        (__attribute__((address_space(3))) unsigned int*)l,
        16, 0, 0);
}

// raw v_exp_f32 — args <= 8 (defer-max THR) so no overflow; very negative
// args underflow to 0 in HW which is exactly softmax semantics.
__device__ __forceinline__ float exp2_raw(float x) {
    return __builtin_amdgcn_exp2f(x);
}

// pack 2 f32 -> dword of 2 fp16 via v_cvt_pkrtz
__device__ __forceinline__ int pkh(float a, float b) {
    fp16x2 v = __builtin_amdgcn_cvt_pkrtz(a, b);
    return __builtin_bit_cast(int, v);
}

// max over a f32x16 accumulator, max3-friendly
__device__ __forceinline__ float maxv16(floatx16 s) {
    float a0 = fmaxf(fmaxf(s[0], s[1]), s[2]);
    float a1 = fmaxf(fmaxf(s[3], s[4]), s[5]);
    float a2 = fmaxf(fmaxf(s[6], s[7]), s[8]);
    float a3 = fmaxf(fmaxf(s[9], s[10]), s[11]);
    float a4 = fmaxf(fmaxf(s[12], s[13]), s[14]);
    float b0 = fmaxf(fmaxf(a0, a1), a2);
    float b1 = fmaxf(fmaxf(a3, a4), s[15]);
    return fmaxf(b0, b1);
}

// Assemble one 16-key B-frag (32x32x16, 8 fp16) from 4 cvtpk dwords.
// (verified rounds 5-8: passes absmax)
__device__ __forceinline__ half8 assembleF(int a, int b, int c, int d) {
    intx2 s1 = __builtin_amdgcn_permlane32_swap(a, c, false, false);
    intx2 s2 = __builtin_amdgcn_permlane32_swap(b, d, false, false);
    intx4 w = {s1[0], s2[0], s1[1], s2[1]};
    return __builtin_bit_cast(half8, w);
}

// ---------------------------------------------------------------------------
// fused fp32 -> fp16 conversion for x, W_attn, W_proj in ONE launch.
// Segment boundaries are multiples of 8*256 so no intra-block divergence.
// ---------------------------------------------------------------------------
#define NX  (BB * TT * CC)        // 8388608
#define NWA (3 * CC * CC)         // 3145728
#define NWP (CC * CC)             // 1048576
__global__ void cvt_all(const float* __restrict__ x, const float* __restrict__ wa,
                        const float* __restrict__ wp,
                        _Float16* __restrict__ xh, _Float16* __restrict__ wah,
                        _Float16* __restrict__ wph) {
    int i = (blockIdx.x * blockDim.x + threadIdx.x) * 8;
    const float* src;
    _Float16* dst;
    int j;
    if (i < NX)            { src = x;  dst = xh;  j = i; }
    else if (i < NX + NWA) { src = wa; dst = wah; j = i - NX; }
    else                   { src = wp; dst = wph; j = i - NX - NWA; }
    float4 v0 = *(const float4*)(src + j);
    float4 v1 = *(const float4*)(src + j + 4);
    half8 h;
    h[0] = (_Float16)v0.x; h[1] = (_Float16)v0.y; h[2] = (_Float16)v0.z; h[3] = (_Float16)v0.w;
    h[4] = (_Float16)v1.x; h[5] = (_Float16)v1.y; h[6] = (_Float16)v1.z; h[7] = (_Float16)v1.w;
    *(half8*)(dst + j) = h;
}

// ---------------------------------------------------------------------------
// NT GEMM: 128x128 tile, BK=64 (proven round-4 structure) + T1 XCD swizzle.
// T1: default dispatch round-robins consecutive blockIdx across the 8 XCDs;
// remap so each XCD gets a contiguous chunk of the grid -> A-panel (2MB)
// stays resident in that XCD's 4MB L2. Requires nwg % 8 == 0 (1536 / 512 ok).
// EPI=0: scatter -> Q(scaled 0.125*log2e)/K/V fp16 [B*H, T, 64]
// EPI=1: fp32 -> c_out[m*N+n]
// ---------------------------------------------------------------------------
template <int EPI>
__global__ __launch_bounds__(256) void hgemm_nt(
    const _Float16* __restrict__ A, const _Float16* __restrict__ Bw,
    const float* __restrict__ bias,
    _Float16* __restrict__ q_out, _Float16* __restrict__ k_out, _Float16* __restrict__ v_out,
    float* __restrict__ c_out,
    int M, int N, int K)
{
    __shared__ __attribute__((aligned(16))) _Float16 As[2 * 128 * 32];  // 16KB
    __shared__ __attribute__((aligned(16))) _Float16 Bs[2 * 128 * 32];  // 16KB

    const int tid  = threadIdx.x;
    const int lane = tid & 63;
    const int wave = tid >> 6;
    const int quad = lane >> 4;
    const int lc   = lane & 15;
    const int wr   = wave >> 1, wc = wave & 1;

    // T1 XCD-aware swizzle (bijective: nwg % 8 == 0)
    const int nwg = gridDim.x * gridDim.y;
    int flat = blockIdx.y * gridDim.x + blockIdx.x;
    flat = (flat & 7) * (nwg >> 3) + (flat >> 3);
    const size_t bm = (size_t)(flat / gridDim.x) * 128;
    const size_t bn = (size_t)(flat % gridDim.x) * 128;

    const int r0 = tid >> 2;        // 0..63
    const int ck = (tid & 3) * 8;   // 0,8,16,24

    const _Float16* Ap = A + (bm + r0) * (size_t)K + ck;
    const _Float16* Bp = Bw + (bn + r0) * (size_t)K + ck;
    _Float16* lA = As + tid * 8;
    _Float16* lB = Bs + tid * 8;
    const size_t rstep = (size_t)64 * K;

    floatx4 acc[4][4] = {};

    for (int kk = 0; kk < K; kk += 64) {
        __syncthreads();
        async_cp16(Ap + kk, lA);
        async_cp16(Ap + kk + rstep, lA + 2048);
        async_cp16(Ap + kk + 32, lA + 4096);
        async_cp16(Ap + kk + 32 + rstep, lA + 4096 + 2048);
        async_cp16(Bp + kk, lB);
        async_cp16(Bp + kk + rstep, lB + 2048);
        async_cp16(Bp + kk + 32, lB + 4096);
        async_cp16(Bp + kk + 32 + rstep, lB + 4096 + 2048);
        __syncthreads();

#pragma unroll
        for (int h = 0; h < 2; h++) {
            half8 af[4], bf[4];
#pragma unroll
            for (int mt = 0; mt < 4; mt++)
                af[mt] = *(const half8*)(As + h * 4096 + (wr * 64 + mt * 16 + lc) * 32 + quad * 8);
#pragma unroll
            for (int nt = 0; nt < 4; nt++)
                bf[nt] = *(const half8*)(Bs + h * 4096 + (wc * 64 + nt * 16 + lc) * 32 + quad * 8);
#pragma unroll
            for (int mt = 0; mt < 4; mt++)
#pragma unroll
                for (int nt = 0; nt < 4; nt++)
                    acc[mt][nt] = __builtin_amdgcn_mfma_f32_16x16x32_f16(af[mt], bf[nt], acc[mt][nt], 0, 0, 0);
        }
    }

#pragma unroll
    for (int mt = 0; mt < 4; mt++) {
        int mbase = (int)bm + wr * 64 + mt * 16 + quad * 4;
#pragma unroll
        for (int nt = 0; nt < 4; nt++) {
            int n = (int)bn + wc * 64 + nt * 16 + lc;
            float bv = bias[n];
#pragma unroll
            for (int r = 0; r < 4; r++) {
                float v = acc[mt][nt][r] + bv;
                int mm = mbase + r;
                if (EPI == 0) {
                    int seg = n >> 10;        // 0=Q 1=K 2=V
                    int cm  = n & 1023;
                    int h = cm >> 6, d = cm & 63;
                    int bb = mm >> 11, t = mm & 2047;
                    size_t dst = (((size_t)(bb * HH + h)) * TT + t) * HD + d;
                    if (seg == 0)      q_out[dst] = (_Float16)(v * 0.18033688f);
                    else if (seg == 1) k_out[dst] = (_Float16)v;
                    else               v_out[dst] = (_Float16)v;
                } else {
                    c_out[(size_t)mm * N + n] = v;
                }
            }
        }
    }
}

// ---------------------------------------------------------------------------
// Flash attention, 32x32 MFMA structure. Grid (B*H, T/256), 512 thr = 8
// waves, 32 queries/wave, key tile = 64.
// Round 9: DOUBLE-BUFFERED K/V LDS -> ONE barrier per tile (was two).
// Between consecutive barriers all waves are in the same iteration; staging
// writes touch buf^1, compute reads touch buf -> disjoint, race-free.
// Waves spread across the whole {write | S^T | softmax | PV} span -> better
// MFMA/VALU cross-wave overlap (floor is the VALU pipe, ~52us).
// ---------------------------------------------------------------------------
__global__ __launch_bounds__(512) void attn_flash(
    const _Float16* __restrict__ Qp, const _Float16* __restrict__ Kp,
    const _Float16* __restrict__ Vp, _Float16* __restrict__ Op)
{
    __shared__ __attribute__((aligned(16))) _Float16 Ks[2][64 * 64];  // 2x8KB
    __shared__ __attribute__((aligned(16))) _Float16 Vt[2][64 * 64];  // 2x8KB

    const int bh   = blockIdx.x;   // 0..63 (b*16+h)
    const int qt   = blockIdx.y;   // 0..7
    const int tid  = threadIdx.x;
    const int lane = tid & 63;
    const int wave = tid >> 6;     // 0..7
    const int ql   = lane & 31;    // query (and dim-row id)
    const int hi   = lane >> 5;    // 0/1

    const size_t hb = (size_t)bh * TT * HD;

    const int qrow = qt * 256 + wave * 32 + ql;
    half8 bq[4];
#pragma unroll
    for (int c = 0; c < 4; c++)
        bq[c] = *(const half8*)(Qp + hb + (size_t)qrow * HD + c * 16 + hi * 8);

    floatx16 o0 = (floatx16)0.0f, o1 = (floatx16)0.0f;
    float mrun = -1e30f, lrun = 0.f;

    // staging maps (512 threads)
    const int sk = tid >> 3;           // K: key 0..63
    const int sj = tid & 7;            // K: dest 16B slot
    const int sg = sj ^ (sk & 7);      // K: source col chunk (pre-swizzled)
    const _Float16* Kg = Kp + hb + (size_t)sk * HD + sg * 8;

    const int vkp = tid >> 4;          // V: key pair 0..31
    const int vd4 = (tid & 15) * 4;    // V: dim group 0..60
    const _Float16* Vg0 = Vp + hb + (size_t)(2 * vkp) * HD + vd4;
    const _Float16* Vg1 = Vg0 + HD;

    // tile 0 -> regs -> buf 0 (visible after first barrier)
    half8 kv  = *(const half8*)Kg;
    half4 va0 = *(const half4*)Vg0;
    half4 vb0 = *(const half4*)Vg1;
    *(half8*)(Ks[0] + tid * 8) = kv;
#pragma unroll
    for (int j = 0; j < 4; j++) {
        int row = vd4 + j;
        int boff = (row * 128 + vkp * 4) ^ (((row >> 2) & 7) << 4);
        half2_t w; w[0] = va0[j]; w[1] = vb0[j];
        *(half2_t*)((char*)Vt[0] + boff) = w;
    }
    // prefetch tile 1 into regs
    {
        const size_t koff = (size_t)64 * HD;
        kv  = *(const half8*)(Kg + koff);
        va0 = *(const half4*)(Vg0 + koff);
        vb0 = *(const half4*)(Vg1 + koff);
    }

    int cur = 0;
    for (int kt = 0; kt < TT; kt += 64) {
        __syncthreads();  // buf[cur] staging visible; prior reads of buf[cur^1] done

        if (kt + 64 < TT) {
            // write tile t+1 (in regs) into buf[cur^1]
            *(half8*)(Ks[cur ^ 1] + tid * 8) = kv;
#pragma unroll
            for (int j = 0; j < 4; j++) {
                int row = vd4 + j;
                int boff = (row * 128 + vkp * 4) ^ (((row >> 2) & 7) << 4);
                half2_t w; w[0] = va0[j]; w[1] = vb0[j];
                *(half2_t*)((char*)Vt[cur ^ 1] + boff) = w;
            }
            // prefetch tile t+2
            if (kt + 128 < TT) {
                const size_t koff = (size_t)(kt + 128) * HD;
                kv  = *(const half8*)(Kg + koff);
                va0 = *(const half4*)(Vg0 + koff);
                vb0 = *(const half4*)(Vg1 + koff);
            }
        }

        const char* Kbuf = (const char*)Ks[cur];
        const char* Vbuf = (const char*)Vt[cur];

        // ---- S^T = K * Q^T : 2 key-blocks x 4 dim-chunks, 32x32x16 ----
        floatx16 s0 = (floatx16)0.0f, s1 = (floatx16)0.0f;
        __builtin_amdgcn_s_setprio(1);
#pragma unroll
        for (int c = 0; c < 4; c++) {
            int offk = (ql * 128 + c * 32 + hi * 16) ^ ((ql & 7) << 4);
            half8 a0 = *(const half8*)(Kbuf + offk);
            half8 a1 = *(const half8*)(Kbuf + offk + 4096);
            s0 = __builtin_amdgcn_mfma_f32_32x32x16_f16(a0, bq[c], s0, 0, 0, 0);
            s1 = __builtin_amdgcn_mfma_f32_32x32x16_f16(a1, bq[c], s1, 0, 0, 0);
        }
        __builtin_amdgcn_s_setprio(0);

        // ---- online softmax: per-lane 32 keys for query q=lane&31 ----
        float mx = fmaxf(maxv16(s0), maxv16(s1));
        mx = fmaxf(mx, __shfl_xor(mx, 32));
        const bool noresc = __all(mx <= mrun + 8.0f);
        const float mnew = noresc ? mrun : fmaxf(mrun, mx);
        float rs = 0.f;
        int d[16];
#pragma unroll
        for (int i = 0; i < 8; i++) {
            float e0 = exp2_raw(s0[2 * i] - mnew);
            float e1 = exp2_raw(s0[2 * i + 1] - mnew);
            rs += e0 + e1;
            d[i] = pkh(e0, e1);
        }
#pragma unroll
        for (int i = 0; i < 8; i++) {
            float e0 = exp2_raw(s1[2 * i] - mnew);
            float e1 = exp2_raw(s1[2 * i + 1] - mnew);
            rs += e0 + e1;
            d[8 + i] = pkh(e0, e1);
        }
        rs += __shfl_xor(rs, 32);
        if (!noresc) {
            float al = exp2_raw(mrun - mnew);
            mrun = mnew;
            lrun *= al;
            o0 *= al;
            o1 *= al;
        }
        lrun += rs;

        // ---- P^T B-frags: 16 keys each, via permlane32_swap ----
        half8 F[4];
        F[0] = assembleF(d[0], d[1], d[2], d[3]);
        F[1] = assembleF(d[4], d[5], d[6], d[7]);
        F[2] = assembleF(d[8], d[9], d[10], d[11]);
        F[3] = assembleF(d[12], d[13], d[14], d[15]);

        // ---- O^T += V^T * P^T : 2 dim-blocks x 4 key-chunks, 32x32x16 ----
        __builtin_amdgcn_s_setprio(1);
#pragma unroll
        for (int kb = 0; kb < 4; kb++) {
            int offv = (ql * 128 + kb * 32 + hi * 16) ^ (((ql >> 2) & 7) << 4);
            half8 v0 = *(const half8*)(Vbuf + offv);
            half8 v1 = *(const half8*)(Vbuf + offv + 4096);
            o0 = __builtin_amdgcn_mfma_f32_32x32x16_f16(v0, F[kb], o0, 0, 0, 0);
            o1 = __builtin_amdgcn_mfma_f32_32x32x16_f16(v1, F[kb], o1, 0, 0, 0);
        }
        __builtin_amdgcn_s_setprio(0);

        cur ^= 1;
    }

    // epilogue: O^T reg r (per dim-block) -> dim = (r&3) + 8*(r>>2) + 4*hi
    const float inv = __builtin_amdgcn_rcpf(lrun);
    const int b = bh >> 4, h = bh & 15;
    size_t base = ((size_t)(b * TT + qrow)) * CC + h * HD;
#pragma unroll
    for (int rr = 0; rr < 4; rr++) {
        half4 hv0, hv1;
#pragma unroll
        for (int t = 0; t < 4; t++) {
            hv0[t] = (_Float16)(o0[rr * 4 + t] * inv);
            hv1[t] = (_Float16)(o1[rr * 4 + t] * inv);
        }
        *(half4*)(Op + base + 8 * rr + 4 * hi) = hv0;
        *(half4*)(Op + base + 32 + 8 * rr + 4 * hi) = hv1;
    }
}

// ---------------------------------------------------------------------------
extern "C" void kernel_launch(void* const* d_in, const int* in_sizes, int n_in,
                              void* d_out, int out_size, void* d_ws, size_t ws_size,
                              hipStream_t stream) {
    const float* x      = (const float*)d_in[0];  // [B,T,C]
    const float* W_attn = (const float*)d_in[1];  // [3C,C]
    const float* b_attn = (const float*)d_in[2];  // [3C]
    const float* W_proj = (const float*)d_in[3];  // [C,C]
    const float* b_proj = (const float*)d_in[4];  // [C]
    float* out = (float*)d_out;

    const size_t SZ_XH  = (size_t)BB * TT * CC * 2;
    const size_t SZ_WA  = (size_t)3 * CC * CC * 2;
    const size_t SZ_WP  = (size_t)CC * CC * 2;
    const size_t SZ_QKV = (size_t)BB * HH * TT * HD * 2;
    size_t off = 0;
    _Float16* xh  = (_Float16*)((char*)d_ws + off); off += SZ_XH;
    _Float16* wah = (_Float16*)((char*)d_ws + off); off += SZ_WA;
    _Float16* wph = (_Float16*)((char*)d_ws + off); off += SZ_WP;
    _Float16* Qh  = (_Float16*)((char*)d_ws + off); off += SZ_QKV;
    _Float16* Kh  = (_Float16*)((char*)d_ws + off); off += SZ_QKV;
    _Float16* Vh  = (_Float16*)((char*)d_ws + off); off += SZ_QKV;
    _Float16* Ah  = (_Float16*)((char*)d_ws + off); off += SZ_XH;
    if (ws_size < off) return;

    const int NTOT = NX + NWA + NWP;  // 12582912, /8/256 = 6144 blocks exact
    cvt_all<<<NTOT / 8 / 256, 256, 0, stream>>>(x, W_attn, W_proj, xh, wah, wph);

    hgemm_nt<0><<<dim3(3 * CC / 128, BB * TT / 128), 256, 0, stream>>>(
        xh, wah, b_attn, Qh, Kh, Vh, nullptr, BB * TT, 3 * CC, CC);

    attn_flash<<<dim3(BB * HH, TT / 256), 512, 0, stream>>>(Qh, Kh, Vh, Ah);

    hgemm_nt<1><<<dim3(CC / 128, BB * TT / 128), 256, 0, stream>>>(
        Ah, wph, b_proj, nullptr, nullptr, nullptr, out, BB * TT, CC, CC);
}